// Round 4
// baseline (561.798 us; speedup 1.0000x reference)
//
#include <hip/hip_runtime.h>
#include <hip/hip_bf16.h>

#define S_LEN 2048
#define DMODEL 1024
#define NHEAD 16
#define DHEAD 64
#define BATCH 4
#define MTOT (BATCH * S_LEN)   // 8192 rows

typedef __attribute__((ext_vector_type(8))) short short8;
typedef __attribute__((ext_vector_type(8))) unsigned short ushort8;
typedef __attribute__((ext_vector_type(4))) unsigned short ushort4v;
typedef __attribute__((ext_vector_type(4))) unsigned int uint4v;
typedef __attribute__((ext_vector_type(4))) float f32x4;

__device__ __forceinline__ unsigned short f2bf(float x) {
    unsigned int u = __float_as_uint(x);
    u += 0x7FFFu + ((u >> 16) & 1u);   // RNE
    return (unsigned short)(u >> 16);
}

__device__ __forceinline__ unsigned int cvt_pk_bf16(float lo, float hi) {
    unsigned int r;
    asm("v_cvt_pk_bf16_f32 %0, %1, %2" : "=v"(r) : "v"(lo), "v"(hi));
    return r;
}

// ---------------- fp32 -> bf16 convert, 3 tensors in one launch ----------------
__global__ __launch_bounds__(256) void k_conv3(const float* __restrict__ s0, const float* __restrict__ s1,
                                               const float* __restrict__ s2,
                                               unsigned short* __restrict__ d0, unsigned short* __restrict__ d1,
                                               unsigned short* __restrict__ d2, int n8) {
    int i = blockIdx.x * 256 + threadIdx.x;
    if (i >= n8) return;
    const float* src = blockIdx.y == 0 ? s0 : (blockIdx.y == 1 ? s1 : s2);
    unsigned short* dst = blockIdx.y == 0 ? d0 : (blockIdx.y == 1 ? d1 : d2);
    const float4* s4 = (const float4*)src;
    float4 a = s4[(size_t)i * 2];
    float4 b = s4[(size_t)i * 2 + 1];
    ushort8 v;
    v[0] = f2bf(a.x); v[1] = f2bf(a.y); v[2] = f2bf(a.z); v[3] = f2bf(a.w);
    v[4] = f2bf(b.x); v[5] = f2bf(b.y); v[6] = f2bf(b.z); v[7] = f2bf(b.w);
    *(ushort8*)(dst + (size_t)i * 8) = v;
}

// ---------------- weight transpose-convert: W[k][n] f32 -> Wt[n][k] bf16 ----------------
__global__ __launch_bounds__(256) void k_transpose_w(const float* __restrict__ W0, const float* __restrict__ W1,
                                                     const float* __restrict__ W2, const float* __restrict__ W3,
                                                     unsigned short* __restrict__ T0, unsigned short* __restrict__ T1,
                                                     unsigned short* __restrict__ T2, unsigned short* __restrict__ T3) {
    const float* src; unsigned short* dst;
    switch (blockIdx.z) {
        case 0: src = W0; dst = T0; break;
        case 1: src = W1; dst = T1; break;
        case 2: src = W2; dst = T2; break;
        default: src = W3; dst = T3; break;
    }
    __shared__ float t[32][33];
    int tx = threadIdx.x & 31, ty = threadIdx.x >> 5;  // 32 x 8
    int n0 = blockIdx.x * 32, k0 = blockIdx.y * 32;
#pragma unroll
    for (int i = 0; i < 32; i += 8)
        t[ty + i][tx] = src[(size_t)(k0 + ty + i) * DMODEL + n0 + tx];
    __syncthreads();
#pragma unroll
    for (int i = 0; i < 32; i += 8)
        dst[(size_t)(n0 + ty + i) * DMODEL + k0 + tx] = f2bf(t[tx][ty + i]);
}

// ================= fused QKV projection GEMM =================
// z==0: Q (alpha folds 1/8 * log2(e) so attention uses exp2 directly)
// z==2 writes V transposed per head: Vt[(b*16+h)*64 + d][s]
__global__ __launch_bounds__(256) void k_gemm_qkv(const unsigned short* __restrict__ Xq,
                                                  const unsigned short* __restrict__ Xk,
                                                  const unsigned short* __restrict__ Xv,
                                                  const unsigned short* __restrict__ Tq,
                                                  const unsigned short* __restrict__ Tk,
                                                  const unsigned short* __restrict__ Tv,
                                                  const float* __restrict__ bqp, const float* __restrict__ bkp,
                                                  const float* __restrict__ bvp,
                                                  unsigned short* __restrict__ Qp, unsigned short* __restrict__ Kp,
                                                  unsigned short* __restrict__ Vt) {
    int z = blockIdx.z;
    const unsigned short* A = z == 0 ? Xq : (z == 1 ? Xk : Xv);
    const unsigned short* Bt = z == 0 ? Tq : (z == 1 ? Tk : Tv);
    const float* bias = z == 0 ? bqp : (z == 1 ? bkp : bvp);
    float alpha = z == 0 ? 0.125f * 1.4426950408889634f : 1.0f;

    __shared__ unsigned short Al[128 * 32];
    __shared__ unsigned short Bl[128 * 32];
    int tid = threadIdx.x;
    int wid = tid >> 6, lane = tid & 63;
    int lr = lane & 15, lg = lane >> 4;
    int lin = blockIdx.y * 8 + blockIdx.x;
    int tile = (lin & 7) * 64 + (lin >> 3);
    int bm = (tile >> 3) * 128, bn = (tile & 7) * 128;
    int wm = (wid >> 1) * 64, wn = (wid & 1) * 64;

    f32x4 acc[4][4];
#pragma unroll
    for (int mt = 0; mt < 4; ++mt)
#pragma unroll
        for (int nt = 0; nt < 4; ++nt) acc[mt][nt] = (f32x4)0.0f;

    for (int k0 = 0; k0 < DMODEL; k0 += 32) {
#pragma unroll
        for (int i = 0; i < 2; ++i) {
            int c = (wid * 2 + i) * 64 + lane;
            int row = c >> 2, cc = c & 3;
            const unsigned short* ga = A + (size_t)(bm + row) * DMODEL + k0 + cc * 8;
            const unsigned short* gb = Bt + (size_t)(bn + row) * DMODEL + k0 + cc * 8;
            __builtin_amdgcn_global_load_lds((const __attribute__((address_space(1))) unsigned int*)ga,
                                             (__attribute__((address_space(3))) unsigned int*)(Al + (wid * 2 + i) * 512),
                                             16, 0, 0);
            __builtin_amdgcn_global_load_lds((const __attribute__((address_space(1))) unsigned int*)gb,
                                             (__attribute__((address_space(3))) unsigned int*)(Bl + (wid * 2 + i) * 512),
                                             16, 0, 0);
        }
        __syncthreads();
        short8 af[4], bf[4];
#pragma unroll
        for (int mt = 0; mt < 4; ++mt)
            af[mt] = *(const short8*)(Al + (wm + mt * 16 + lr) * 32 + lg * 8);
#pragma unroll
        for (int nt = 0; nt < 4; ++nt)
            bf[nt] = *(const short8*)(Bl + (wn + nt * 16 + lr) * 32 + lg * 8);
        __builtin_amdgcn_s_setprio(1);
#pragma unroll
        for (int mt = 0; mt < 4; ++mt)
#pragma unroll
            for (int nt = 0; nt < 4; ++nt)
                acc[mt][nt] = __builtin_amdgcn_mfma_f32_16x16x32_bf16(af[mt], bf[nt], acc[mt][nt], 0, 0, 0);
        __builtin_amdgcn_s_setprio(0);
        __syncthreads();
    }

#pragma unroll
    for (int nt = 0; nt < 4; ++nt) {
        int col = bn + wn + nt * 16 + lr;
        float bv = bias[col];
#pragma unroll
        for (int mt = 0; mt < 4; ++mt) {
#pragma unroll
            for (int r = 0; r < 4; ++r) {
                int row = bm + wm + mt * 16 + lg * 4 + r;
                float v = (acc[mt][nt][r] + bv) * alpha;
                if (z < 2) {
                    unsigned short* dst = z == 0 ? Qp : Kp;
                    dst[(size_t)row * DMODEL + col] = f2bf(v);
                } else {
                    int h = col >> 6, d = col & 63;
                    int b = row >> 11, s = row & 2047;
                    Vt[((size_t)(b * NHEAD + h) * DHEAD + d) * S_LEN + s] = f2bf(v);
                }
            }
        }
    }
}

// ---------------- output projection GEMM (fp32 out) ----------------
__global__ __launch_bounds__(256) void k_gemm_out(const unsigned short* __restrict__ A,
                                                  const unsigned short* __restrict__ Bt,
                                                  const float* __restrict__ bias,
                                                  float* __restrict__ Cout) {
    __shared__ unsigned short Al[128 * 32];
    __shared__ unsigned short Bl[128 * 32];
    int tid = threadIdx.x;
    int wid = tid >> 6, lane = tid & 63;
    int lr = lane & 15, lg = lane >> 4;
    int lin = blockIdx.y * 8 + blockIdx.x;
    int tile = (lin & 7) * 64 + (lin >> 3);
    int bm = (tile >> 3) * 128, bn = (tile & 7) * 128;
    int wm = (wid >> 1) * 64, wn = (wid & 1) * 64;

    f32x4 acc[4][4];
#pragma unroll
    for (int mt = 0; mt < 4; ++mt)
#pragma unroll
        for (int nt = 0; nt < 4; ++nt) acc[mt][nt] = (f32x4)0.0f;

    for (int k0 = 0; k0 < DMODEL; k0 += 32) {
#pragma unroll
        for (int i = 0; i < 2; ++i) {
            int c = (wid * 2 + i) * 64 + lane;
            int row = c >> 2, cc = c & 3;
            const unsigned short* ga = A + (size_t)(bm + row) * DMODEL + k0 + cc * 8;
            const unsigned short* gb = Bt + (size_t)(bn + row) * DMODEL + k0 + cc * 8;
            __builtin_amdgcn_global_load_lds((const __attribute__((address_space(1))) unsigned int*)ga,
                                             (__attribute__((address_space(3))) unsigned int*)(Al + (wid * 2 + i) * 512),
                                             16, 0, 0);
            __builtin_amdgcn_global_load_lds((const __attribute__((address_space(1))) unsigned int*)gb,
                                             (__attribute__((address_space(3))) unsigned int*)(Bl + (wid * 2 + i) * 512),
                                             16, 0, 0);
        }
        __syncthreads();
        short8 af[4], bf[4];
#pragma unroll
        for (int mt = 0; mt < 4; ++mt)
            af[mt] = *(const short8*)(Al + (wm + mt * 16 + lr) * 32 + lg * 8);
#pragma unroll
        for (int nt = 0; nt < 4; ++nt)
            bf[nt] = *(const short8*)(Bl + (wn + nt * 16 + lr) * 32 + lg * 8);
        __builtin_amdgcn_s_setprio(1);
#pragma unroll
        for (int mt = 0; mt < 4; ++mt)
#pragma unroll
            for (int nt = 0; nt < 4; ++nt)
                acc[mt][nt] = __builtin_amdgcn_mfma_f32_16x16x32_bf16(af[mt], bf[nt], acc[mt][nt], 0, 0, 0);
        __builtin_amdgcn_s_setprio(0);
        __syncthreads();
    }

#pragma unroll
    for (int nt = 0; nt < 4; ++nt) {
        int col = bn + wn + nt * 16 + lr;
        float bv = bias[col];
#pragma unroll
        for (int mt = 0; mt < 4; ++mt)
#pragma unroll
            for (int r = 0; r < 4; ++r) {
                int row = bm + wm + mt * 16 + lg * 4 + r;
                Cout[(size_t)row * DMODEL + col] = acc[mt][nt][r] + bv;
            }
    }
}

// ================= causal flash attention, 2-wave split-K workgroups =================
// Workgroup = 128 threads = 2 waves, one (head, 64-row q-block) pair.
// Wave w handles kb = w, w+2, ... (interleaved split-K); merge (m,l,ctx) via LDS at end.
// Scores arrive pre-scaled by log2(e)/8 so softmax uses exp2 directly.
__global__ __launch_bounds__(128, 4) void k_attn(const unsigned short* __restrict__ Qp,
                                                 const unsigned short* __restrict__ Kp,
                                                 const unsigned short* __restrict__ Vt,
                                                 unsigned short* __restrict__ Ctx) {
    __shared__ f32x4 cbuf[4][4][64];
    __shared__ float mbuf[4][64];
    __shared__ float lbuf[4][64];

    int tid = threadIdx.x;
    int wid = tid >> 6;                   // 0 or 1
    int lane = tid & 63;
    int lr = lane & 15, lg = lane >> 4;
    int bid = blockIdx.x;                 // 0..2047
    int xcd = bid & 7;
    int j = bid >> 3;                     // 0..255
    int bh = xcd + 8 * (j & 7);           // 8 heads per XCD (K+V ~4MB = one L2)
    int qb = (S_LEN / 64 - 1) - (j >> 3); // biggest q-block first
    int b = bh >> 4, h = bh & 15;
    size_t baserow = (size_t)b * S_LEN;
    int hcol = h * DHEAD;

    short8 qf[4][2];
#pragma unroll
    for (int qt = 0; qt < 4; ++qt)
#pragma unroll
        for (int ks = 0; ks < 2; ++ks)
            qf[qt][ks] = *(const short8*)(Qp + (baserow + qb * 64 + qt * 16 + lr) * DMODEL + hcol + ks * 32 + lg * 8);

    f32x4 ctx[4][4];   // [dt][qt]
#pragma unroll
    for (int dt = 0; dt < 4; ++dt)
#pragma unroll
        for (int qt = 0; qt < 4; ++qt) ctx[dt][qt] = (f32x4)0.0f;

    float mrun[4], lrun[4];
#pragma unroll
    for (int qt = 0; qt < 4; ++qt) { mrun[qt] = -1e30f; lrun[qt] = 0.0f; }

    const unsigned short* vth = Vt + (size_t)bh * DHEAD * S_LEN;

    for (int kb = wid; kb <= qb; kb += 2) {
        // ---- S^T = K * Q^T ----
        f32x4 s[4][4];
#pragma unroll
        for (int kt = 0; kt < 4; ++kt)
#pragma unroll
            for (int qt = 0; qt < 4; ++qt) s[kt][qt] = (f32x4)0.0f;
#pragma unroll
        for (int kt = 0; kt < 4; ++kt) {
            short8 kf[2];
#pragma unroll
            for (int ks = 0; ks < 2; ++ks)
                kf[ks] = *(const short8*)(Kp + (baserow + kb * 64 + kt * 16 + lr) * DMODEL + hcol + ks * 32 + lg * 8);
            __builtin_amdgcn_s_setprio(1);
#pragma unroll
            for (int qt = 0; qt < 4; ++qt)
#pragma unroll
                for (int ks = 0; ks < 2; ++ks)
                    s[kt][qt] = __builtin_amdgcn_mfma_f32_16x16x32_bf16(kf[ks], qf[qt][ks], s[kt][qt], 0, 0, 0);
            __builtin_amdgcn_s_setprio(0);
        }

        if (kb == qb) {   // causal mask inside diagonal block
#pragma unroll
            for (int kt = 0; kt < 4; ++kt)
#pragma unroll
                for (int qt = 0; qt < 4; ++qt)
#pragma unroll
                    for (int r = 0; r < 4; ++r)
                        if (kt * 16 + lg * 4 + r > qt * 16 + lr) s[kt][qt][r] = -1e30f;
        }

        // ---- online softmax (log2 domain) + P^T pack via cvt_pk ----
        unsigned int pw[4][2][4];   // [qt][ks][word]
#pragma unroll
        for (int qt = 0; qt < 4; ++qt) {
            float m0 = fmaxf(fmaxf(s[0][qt][0], s[0][qt][1]), fmaxf(s[0][qt][2], s[0][qt][3]));
            float m1 = fmaxf(fmaxf(s[1][qt][0], s[1][qt][1]), fmaxf(s[1][qt][2], s[1][qt][3]));
            float m2 = fmaxf(fmaxf(s[2][qt][0], s[2][qt][1]), fmaxf(s[2][qt][2], s[2][qt][3]));
            float m3 = fmaxf(fmaxf(s[3][qt][0], s[3][qt][1]), fmaxf(s[3][qt][2], s[3][qt][3]));
            float mx = fmaxf(fmaxf(m0, m1), fmaxf(m2, m3));
            mx = fmaxf(mx, __shfl_xor(mx, 16));
            mx = fmaxf(mx, __shfl_xor(mx, 32));
            // defer-max: only rescale when the max grew by > 8 (log2 units) on some lane
            unsigned long long grow = __ballot(mx > mrun[qt] + 8.0f);
            if (grow) {
                float mnew = fmaxf(mrun[qt], mx);
                float scale = exp2f(mrun[qt] - mnew);
                mrun[qt] = mnew;
                lrun[qt] *= scale;
#pragma unroll
                for (int dt = 0; dt < 4; ++dt)
#pragma unroll
                    for (int r = 0; r < 4; ++r) ctx[dt][qt][r] *= scale;
            }
            float m = mrun[qt];
#pragma unroll
            for (int kt = 0; kt < 4; ++kt)
#pragma unroll
                for (int r = 0; r < 4; ++r) s[kt][qt][r] = exp2f(s[kt][qt][r] - m);
            float r0 = (s[0][qt][0] + s[0][qt][1]) + (s[0][qt][2] + s[0][qt][3]);
            float r1 = (s[1][qt][0] + s[1][qt][1]) + (s[1][qt][2] + s[1][qt][3]);
            float r2 = (s[2][qt][0] + s[2][qt][1]) + (s[2][qt][2] + s[2][qt][3]);
            float r3 = (s[3][qt][0] + s[3][qt][1]) + (s[3][qt][2] + s[3][qt][3]);
            float rs = (r0 + r1) + (r2 + r3);
            rs += __shfl_xor(rs, 16);
            rs += __shfl_xor(rs, 32);
            lrun[qt] += rs;
#pragma unroll
            for (int ks = 0; ks < 2; ++ks) {
                pw[qt][ks][0] = cvt_pk_bf16(s[2 * ks][qt][0], s[2 * ks][qt][1]);
                pw[qt][ks][1] = cvt_pk_bf16(s[2 * ks][qt][2], s[2 * ks][qt][3]);
                pw[qt][ks][2] = cvt_pk_bf16(s[2 * ks + 1][qt][0], s[2 * ks + 1][qt][1]);
                pw[qt][ks][3] = cvt_pk_bf16(s[2 * ks + 1][qt][2], s[2 * ks + 1][qt][3]);
            }
        }

        // ---- ctx^T += V^T * P^T  (k-slot bijection kk = 32ks + 16(j>>2) + 4lg + (j&3)) ----
#pragma unroll
        for (int dt = 0; dt < 4; ++dt) {
            const unsigned short* vrow = vth + (size_t)(dt * 16 + lr) * S_LEN + kb * 64 + 4 * lg;
#pragma unroll
            for (int ks = 0; ks < 2; ++ks) {
                ushort4v lo = *(const ushort4v*)(vrow + 32 * ks);
                ushort4v hi = *(const ushort4v*)(vrow + 32 * ks + 16);
                short8 vf;
                vf[0] = (short)lo[0]; vf[1] = (short)lo[1]; vf[2] = (short)lo[2]; vf[3] = (short)lo[3];
                vf[4] = (short)hi[0]; vf[5] = (short)hi[1]; vf[6] = (short)hi[2]; vf[7] = (short)hi[3];
                __builtin_amdgcn_s_setprio(1);
#pragma unroll
                for (int qt = 0; qt < 4; ++qt) {
                    uint4v w = {pw[qt][ks][0], pw[qt][ks][1], pw[qt][ks][2], pw[qt][ks][3]};
                    ctx[dt][qt] = __builtin_amdgcn_mfma_f32_16x16x32_bf16(vf, __builtin_bit_cast(short8, w),
                                                                          ctx[dt][qt], 0, 0, 0);
                }
                __builtin_amdgcn_s_setprio(0);
            }
        }
    }

    // ---- merge wave1 into wave0 via LDS, then normalize + store ----
    if (wid == 1) {
#pragma unroll
        for (int dt = 0; dt < 4; ++dt)
#pragma unroll
            for (int qt = 0; qt < 4; ++qt) cbuf[dt][qt][lane] = ctx[dt][qt];
#pragma unroll
        for (int qt = 0; qt < 4; ++qt) { mbuf[qt][lane] = mrun[qt]; lbuf[qt][lane] = lrun[qt]; }
    }
    __syncthreads();
    if (wid == 0) {
#pragma unroll
        for (int qt = 0; qt < 4; ++qt) {
            float m1 = mbuf[qt][lane], l1 = lbuf[qt][lane];
            float mM = fmaxf(mrun[qt], m1);
            float s0 = exp2f(mrun[qt] - mM), s1 = exp2f(m1 - mM);
            float linv = 1.0f / (lrun[qt] * s0 + l1 * s1);
            float f0 = s0 * linv, f1 = s1 * linv;
#pragma unroll
            for (int dt = 0; dt < 4; ++dt) {
                f32x4 o1 = cbuf[dt][qt][lane];
                float o0 = ctx[dt][qt][0] * f0 + o1[0] * f1;
                float o1v = ctx[dt][qt][1] * f0 + o1[1] * f1;
                float o2 = ctx[dt][qt][2] * f0 + o1[2] * f1;
                float o3 = ctx[dt][qt][3] * f0 + o1[3] * f1;
                unsigned int lo = (unsigned int)f2bf(o0) | ((unsigned int)f2bf(o1v) << 16);
                unsigned int hi = (unsigned int)f2bf(o2) | ((unsigned int)f2bf(o3) << 16);
                uint2 vv; vv.x = lo; vv.y = hi;
                *(uint2*)(Ctx + (baserow + qb * 64 + qt * 16 + lr) * DMODEL + hcol + dt * 16 + lg * 4) = vv;
            }
        }
    }
}

// ---------------- host launch ----------------
extern "C" void kernel_launch(void* const* d_in, const int* in_sizes, int n_in,
                              void* d_out, int out_size, void* d_ws, size_t ws_size,
                              hipStream_t stream) {
    const float* q_in = (const float*)d_in[0];
    const float* k_in = (const float*)d_in[1];
    const float* v_in = (const float*)d_in[2];
    const float* Wq = (const float*)d_in[4];
    const float* bq = (const float*)d_in[5];
    const float* Wk = (const float*)d_in[6];
    const float* bk = (const float*)d_in[7];
    const float* Wv = (const float*)d_in[8];
    const float* bv = (const float*)d_in[9];
    const float* Wo = (const float*)d_in[10];
    const float* bo = (const float*)d_in[11];

    char* ws = (char*)d_ws;
    const size_t SZ_ACT = (size_t)MTOT * DMODEL * 2;
    const size_t SZ_W = (size_t)DMODEL * DMODEL * 2;
    unsigned short* Xq = (unsigned short*)(ws);
    unsigned short* Xk = (unsigned short*)(ws + SZ_ACT);
    unsigned short* Xv = (unsigned short*)(ws + 2 * SZ_ACT);
    unsigned short* Tq = (unsigned short*)(ws + 3 * SZ_ACT);
    unsigned short* Tk = (unsigned short*)(ws + 3 * SZ_ACT + SZ_W);
    unsigned short* Tv = (unsigned short*)(ws + 3 * SZ_ACT + 2 * SZ_W);
    unsigned short* To = (unsigned short*)(ws + 3 * SZ_ACT + 3 * SZ_W);
    unsigned short* Qp = (unsigned short*)(ws + 3 * SZ_ACT + 4 * SZ_W);
    unsigned short* Kp = (unsigned short*)(ws + 4 * SZ_ACT + 4 * SZ_W);
    unsigned short* Vt = (unsigned short*)(ws + 5 * SZ_ACT + 4 * SZ_W);
    unsigned short* Cx = (unsigned short*)(ws + 6 * SZ_ACT + 4 * SZ_W);

    int n8 = MTOT * DMODEL / 8;
    k_conv3<<<dim3((n8 + 255) / 256, 3), 256, 0, stream>>>(q_in, k_in, v_in, Xq, Xk, Xv, n8);
    k_transpose_w<<<dim3(32, 32, 4), 256, 0, stream>>>(Wq, Wk, Wv, Wo, Tq, Tk, Tv, To);

    k_gemm_qkv<<<dim3(8, 64, 3), 256, 0, stream>>>(Xq, Xk, Xv, Tq, Tk, Tv, bq, bk, bv, Qp, Kp, Vt);

    k_attn<<<dim3((S_LEN / 64) * BATCH * NHEAD), 128, 0, stream>>>(Qp, Kp, Vt, Cx);

    k_gemm_out<<<dim3(8, 64), 256, 0, stream>>>(Cx, To, bo, (float*)d_out);
}

// Round 6
// 476.309 us; speedup vs baseline: 1.1795x; 1.1795x over previous
//
#include <hip/hip_runtime.h>
#include <hip/hip_bf16.h>

#define S_LEN 2048
#define DMODEL 1024
#define NHEAD 16
#define DHEAD 64
#define BATCH 4
#define MTOT (BATCH * S_LEN)   // 8192 rows

typedef __attribute__((ext_vector_type(8))) short short8;
typedef __attribute__((ext_vector_type(8))) unsigned short ushort8;
typedef __attribute__((ext_vector_type(4))) unsigned short ushort4v;
typedef __attribute__((ext_vector_type(4))) unsigned int uint4v;
typedef __attribute__((ext_vector_type(4))) float f32x4;

__device__ __forceinline__ unsigned short f2bf(float x) {
    unsigned int u = __float_as_uint(x);
    u += 0x7FFFu + ((u >> 16) & 1u);   // RNE
    return (unsigned short)(u >> 16);
}

__device__ __forceinline__ unsigned int cvt_pk_bf16(float lo, float hi) {
    unsigned int r;
    asm("v_cvt_pk_bf16_f32 %0, %1, %2" : "=v"(r) : "v"(lo), "v"(hi));
    return r;
}

// ---------------- fp32 -> bf16 convert, 3 tensors in one launch ----------------
__global__ __launch_bounds__(256) void k_conv3(const float* __restrict__ s0, const float* __restrict__ s1,
                                               const float* __restrict__ s2,
                                               unsigned short* __restrict__ d0, unsigned short* __restrict__ d1,
                                               unsigned short* __restrict__ d2, int n8) {
    int i = blockIdx.x * 256 + threadIdx.x;
    if (i >= n8) return;
    const float* src = blockIdx.y == 0 ? s0 : (blockIdx.y == 1 ? s1 : s2);
    unsigned short* dst = blockIdx.y == 0 ? d0 : (blockIdx.y == 1 ? d1 : d2);
    const float4* s4 = (const float4*)src;
    float4 a = s4[(size_t)i * 2];
    float4 b = s4[(size_t)i * 2 + 1];
    ushort8 v;
    v[0] = f2bf(a.x); v[1] = f2bf(a.y); v[2] = f2bf(a.z); v[3] = f2bf(a.w);
    v[4] = f2bf(b.x); v[5] = f2bf(b.y); v[6] = f2bf(b.z); v[7] = f2bf(b.w);
    *(ushort8*)(dst + (size_t)i * 8) = v;
}

// ---------------- weight transpose-convert: W[k][n] f32 -> Wt[n][k] bf16 ----------------
__global__ __launch_bounds__(256) void k_transpose_w(const float* __restrict__ W0, const float* __restrict__ W1,
                                                     const float* __restrict__ W2, const float* __restrict__ W3,
                                                     unsigned short* __restrict__ T0, unsigned short* __restrict__ T1,
                                                     unsigned short* __restrict__ T2, unsigned short* __restrict__ T3) {
    const float* src; unsigned short* dst;
    switch (blockIdx.z) {
        case 0: src = W0; dst = T0; break;
        case 1: src = W1; dst = T1; break;
        case 2: src = W2; dst = T2; break;
        default: src = W3; dst = T3; break;
    }
    __shared__ float t[32][33];
    int tx = threadIdx.x & 31, ty = threadIdx.x >> 5;  // 32 x 8
    int n0 = blockIdx.x * 32, k0 = blockIdx.y * 32;
#pragma unroll
    for (int i = 0; i < 32; i += 8)
        t[ty + i][tx] = src[(size_t)(k0 + ty + i) * DMODEL + n0 + tx];
    __syncthreads();
#pragma unroll
    for (int i = 0; i < 32; i += 8)
        dst[(size_t)(n0 + ty + i) * DMODEL + k0 + tx] = f2bf(t[tx][ty + i]);
}

// ================= fused QKV projection GEMM =================
// z==0: Q (alpha folds 1/8 * log2(e) so attention uses exp2 directly)
// z==2 writes V transposed per head: Vt[(b*16+h)*64 + d][s]
__global__ __launch_bounds__(256) void k_gemm_qkv(const unsigned short* __restrict__ Xq,
                                                  const unsigned short* __restrict__ Xk,
                                                  const unsigned short* __restrict__ Xv,
                                                  const unsigned short* __restrict__ Tq,
                                                  const unsigned short* __restrict__ Tk,
                                                  const unsigned short* __restrict__ Tv,
                                                  const float* __restrict__ bqp, const float* __restrict__ bkp,
                                                  const float* __restrict__ bvp,
                                                  unsigned short* __restrict__ Qp, unsigned short* __restrict__ Kp,
                                                  unsigned short* __restrict__ Vt) {
    int z = blockIdx.z;
    const unsigned short* A = z == 0 ? Xq : (z == 1 ? Xk : Xv);
    const unsigned short* Bt = z == 0 ? Tq : (z == 1 ? Tk : Tv);
    const float* bias = z == 0 ? bqp : (z == 1 ? bkp : bvp);
    float alpha = z == 0 ? 0.125f * 1.4426950408889634f : 1.0f;

    __shared__ unsigned short Al[128 * 32];
    __shared__ unsigned short Bl[128 * 32];
    int tid = threadIdx.x;
    int wid = tid >> 6, lane = tid & 63;
    int lr = lane & 15, lg = lane >> 4;
    int lin = blockIdx.y * 8 + blockIdx.x;
    int tile = (lin & 7) * 64 + (lin >> 3);
    int bm = (tile >> 3) * 128, bn = (tile & 7) * 128;
    int wm = (wid >> 1) * 64, wn = (wid & 1) * 64;

    f32x4 acc[4][4];
#pragma unroll
    for (int mt = 0; mt < 4; ++mt)
#pragma unroll
        for (int nt = 0; nt < 4; ++nt) acc[mt][nt] = (f32x4)0.0f;

    for (int k0 = 0; k0 < DMODEL; k0 += 32) {
#pragma unroll
        for (int i = 0; i < 2; ++i) {
            int c = (wid * 2 + i) * 64 + lane;
            int row = c >> 2, cc = c & 3;
            const unsigned short* ga = A + (size_t)(bm + row) * DMODEL + k0 + cc * 8;
            const unsigned short* gb = Bt + (size_t)(bn + row) * DMODEL + k0 + cc * 8;
            __builtin_amdgcn_global_load_lds((const __attribute__((address_space(1))) unsigned int*)ga,
                                             (__attribute__((address_space(3))) unsigned int*)(Al + (wid * 2 + i) * 512),
                                             16, 0, 0);
            __builtin_amdgcn_global_load_lds((const __attribute__((address_space(1))) unsigned int*)gb,
                                             (__attribute__((address_space(3))) unsigned int*)(Bl + (wid * 2 + i) * 512),
                                             16, 0, 0);
        }
        __syncthreads();
        short8 af[4], bf[4];
#pragma unroll
        for (int mt = 0; mt < 4; ++mt)
            af[mt] = *(const short8*)(Al + (wm + mt * 16 + lr) * 32 + lg * 8);
#pragma unroll
        for (int nt = 0; nt < 4; ++nt)
            bf[nt] = *(const short8*)(Bl + (wn + nt * 16 + lr) * 32 + lg * 8);
        __builtin_amdgcn_s_setprio(1);
#pragma unroll
        for (int mt = 0; mt < 4; ++mt)
#pragma unroll
            for (int nt = 0; nt < 4; ++nt)
                acc[mt][nt] = __builtin_amdgcn_mfma_f32_16x16x32_bf16(af[mt], bf[nt], acc[mt][nt], 0, 0, 0);
        __builtin_amdgcn_s_setprio(0);
        __syncthreads();
    }

#pragma unroll
    for (int nt = 0; nt < 4; ++nt) {
        int col = bn + wn + nt * 16 + lr;
        float bv = bias[col];
#pragma unroll
        for (int mt = 0; mt < 4; ++mt) {
#pragma unroll
            for (int r = 0; r < 4; ++r) {
                int row = bm + wm + mt * 16 + lg * 4 + r;
                float v = (acc[mt][nt][r] + bv) * alpha;
                if (z < 2) {
                    unsigned short* dst = z == 0 ? Qp : Kp;
                    dst[(size_t)row * DMODEL + col] = f2bf(v);
                } else {
                    int h = col >> 6, d = col & 63;
                    int b = row >> 11, s = row & 2047;
                    Vt[((size_t)(b * NHEAD + h) * DHEAD + d) * S_LEN + s] = f2bf(v);
                }
            }
        }
    }
}

// ---------------- output projection GEMM (fp32 out) ----------------
__global__ __launch_bounds__(256) void k_gemm_out(const unsigned short* __restrict__ A,
                                                  const unsigned short* __restrict__ Bt,
                                                  const float* __restrict__ bias,
                                                  float* __restrict__ Cout) {
    __shared__ unsigned short Al[128 * 32];
    __shared__ unsigned short Bl[128 * 32];
    int tid = threadIdx.x;
    int wid = tid >> 6, lane = tid & 63;
    int lr = lane & 15, lg = lane >> 4;
    int lin = blockIdx.y * 8 + blockIdx.x;
    int tile = (lin & 7) * 64 + (lin >> 3);
    int bm = (tile >> 3) * 128, bn = (tile & 7) * 128;
    int wm = (wid >> 1) * 64, wn = (wid & 1) * 64;

    f32x4 acc[4][4];
#pragma unroll
    for (int mt = 0; mt < 4; ++mt)
#pragma unroll
        for (int nt = 0; nt < 4; ++nt) acc[mt][nt] = (f32x4)0.0f;

    for (int k0 = 0; k0 < DMODEL; k0 += 32) {
#pragma unroll
        for (int i = 0; i < 2; ++i) {
            int c = (wid * 2 + i) * 64 + lane;
            int row = c >> 2, cc = c & 3;
            const unsigned short* ga = A + (size_t)(bm + row) * DMODEL + k0 + cc * 8;
            const unsigned short* gb = Bt + (size_t)(bn + row) * DMODEL + k0 + cc * 8;
            __builtin_amdgcn_global_load_lds((const __attribute__((address_space(1))) unsigned int*)ga,
                                             (__attribute__((address_space(3))) unsigned int*)(Al + (wid * 2 + i) * 512),
                                             16, 0, 0);
            __builtin_amdgcn_global_load_lds((const __attribute__((address_space(1))) unsigned int*)gb,
                                             (__attribute__((address_space(3))) unsigned int*)(Bl + (wid * 2 + i) * 512),
                                             16, 0, 0);
        }
        __syncthreads();
        short8 af[4], bf[4];
#pragma unroll
        for (int mt = 0; mt < 4; ++mt)
            af[mt] = *(const short8*)(Al + (wm + mt * 16 + lr) * 32 + lg * 8);
#pragma unroll
        for (int nt = 0; nt < 4; ++nt)
            bf[nt] = *(const short8*)(Bl + (wn + nt * 16 + lr) * 32 + lg * 8);
        __builtin_amdgcn_s_setprio(1);
#pragma unroll
        for (int mt = 0; mt < 4; ++mt)
#pragma unroll
            for (int nt = 0; nt < 4; ++nt)
                acc[mt][nt] = __builtin_amdgcn_mfma_f32_16x16x32_bf16(af[mt], bf[nt], acc[mt][nt], 0, 0, 0);
        __builtin_amdgcn_s_setprio(0);
        __syncthreads();
    }

#pragma unroll
    for (int nt = 0; nt < 4; ++nt) {
        int col = bn + wn + nt * 16 + lr;
        float bv = bias[col];
#pragma unroll
        for (int mt = 0; mt < 4; ++mt)
#pragma unroll
            for (int r = 0; r < 4; ++r) {
                int row = bm + wm + mt * 16 + lg * 4 + r;
                Cout[(size_t)row * DMODEL + col] = acc[mt][nt][r] + bv;
            }
    }
}

// ================= causal flash attention, 2-wave split-K workgroups =================
// Workgroup = 128 threads = 2 waves, one (head, 64-row q-block) pair.
// Wave w handles kb = w, w+2, ... (interleaved split-K); merge (m,l,ctx) via LDS at end.
// Scores arrive pre-scaled by log2(e)/8 so softmax uses exp2 directly.
// NOTE: no min-waves arg in launch_bounds — forcing occupancy caused 64/84-VGPR clamps
// and catastrophic scratch spill (R2: 280MB, R4: 1GB per dispatch). Let the allocator run free.
__global__ __launch_bounds__(128) void k_attn(const unsigned short* __restrict__ Qp,
                                              const unsigned short* __restrict__ Kp,
                                              const unsigned short* __restrict__ Vt,
                                              unsigned short* __restrict__ Ctx) {
    __shared__ f32x4 cbuf[4][4][64];
    __shared__ float mbuf[4][64];
    __shared__ float lbuf[4][64];

    int tid = threadIdx.x;
    int wid = tid >> 6;                   // 0 or 1
    int lane = tid & 63;
    int lr = lane & 15, lg = lane >> 4;
    int bid = blockIdx.x;                 // 0..2047
    int xcd = bid & 7;
    int j = bid >> 3;                     // 0..255
    int bh = xcd + 8 * (j & 7);           // 8 heads per XCD (K+V ~4MB = one L2)
    int qb = (S_LEN / 64 - 1) - (j >> 3); // biggest q-block first
    int b = bh >> 4, h = bh & 15;
    size_t baserow = (size_t)b * S_LEN;
    int hcol = h * DHEAD;

    short8 qf[4][2];
#pragma unroll
    for (int qt = 0; qt < 4; ++qt)
#pragma unroll
        for (int ks = 0; ks < 2; ++ks)
            qf[qt][ks] = *(const short8*)(Qp + (baserow + qb * 64 + qt * 16 + lr) * DMODEL + hcol + ks * 32 + lg * 8);

    f32x4 ctx[4][4];   // [dt][qt]
#pragma unroll
    for (int dt = 0; dt < 4; ++dt)
#pragma unroll
        for (int qt = 0; qt < 4; ++qt) ctx[dt][qt] = (f32x4)0.0f;

    float mrun[4], lrun[4];
#pragma unroll
    for (int qt = 0; qt < 4; ++qt) { mrun[qt] = -1e30f; lrun[qt] = 0.0f; }

    const unsigned short* vth = Vt + (size_t)bh * DHEAD * S_LEN;

    for (int kb = wid; kb <= qb; kb += 2) {
        // ---- S^T = K * Q^T ----
        f32x4 s[4][4];
#pragma unroll
        for (int kt = 0; kt < 4; ++kt)
#pragma unroll
            for (int qt = 0; qt < 4; ++qt) s[kt][qt] = (f32x4)0.0f;
#pragma unroll
        for (int kt = 0; kt < 4; ++kt) {
            short8 kf[2];
#pragma unroll
            for (int ks = 0; ks < 2; ++ks)
                kf[ks] = *(const short8*)(Kp + (baserow + kb * 64 + kt * 16 + lr) * DMODEL + hcol + ks * 32 + lg * 8);
            __builtin_amdgcn_s_setprio(1);
#pragma unroll
            for (int qt = 0; qt < 4; ++qt)
#pragma unroll
                for (int ks = 0; ks < 2; ++ks)
                    s[kt][qt] = __builtin_amdgcn_mfma_f32_16x16x32_bf16(kf[ks], qf[qt][ks], s[kt][qt], 0, 0, 0);
            __builtin_amdgcn_s_setprio(0);
        }

        if (kb == qb) {   // causal mask inside diagonal block
#pragma unroll
            for (int kt = 0; kt < 4; ++kt)
#pragma unroll
                for (int qt = 0; qt < 4; ++qt)
#pragma unroll
                    for (int r = 0; r < 4; ++r)
                        if (kt * 16 + lg * 4 + r > qt * 16 + lr) s[kt][qt][r] = -1e30f;
        }

        // ---- online softmax (log2 domain) + P^T pack via cvt_pk ----
        unsigned int pw[4][2][4];   // [qt][ks][word]
#pragma unroll
        for (int qt = 0; qt < 4; ++qt) {
            float m0 = fmaxf(fmaxf(s[0][qt][0], s[0][qt][1]), fmaxf(s[0][qt][2], s[0][qt][3]));
            float m1 = fmaxf(fmaxf(s[1][qt][0], s[1][qt][1]), fmaxf(s[1][qt][2], s[1][qt][3]));
            float m2 = fmaxf(fmaxf(s[2][qt][0], s[2][qt][1]), fmaxf(s[2][qt][2], s[2][qt][3]));
            float m3 = fmaxf(fmaxf(s[3][qt][0], s[3][qt][1]), fmaxf(s[3][qt][2], s[3][qt][3]));
            float mx = fmaxf(fmaxf(m0, m1), fmaxf(m2, m3));
            mx = fmaxf(mx, __shfl_xor(mx, 16));
            mx = fmaxf(mx, __shfl_xor(mx, 32));
            // defer-max: only rescale when the max grew by > 8 (log2 units) on some lane
            unsigned long long grow = __ballot(mx > mrun[qt] + 8.0f);
            if (grow) {
                float mnew = fmaxf(mrun[qt], mx);
                float scale = exp2f(mrun[qt] - mnew);
                mrun[qt] = mnew;
                lrun[qt] *= scale;
#pragma unroll
                for (int dt = 0; dt < 4; ++dt)
#pragma unroll
                    for (int r = 0; r < 4; ++r) ctx[dt][qt][r] *= scale;
            }
            float m = mrun[qt];
#pragma unroll
            for (int kt = 0; kt < 4; ++kt)
#pragma unroll
                for (int r = 0; r < 4; ++r) s[kt][qt][r] = exp2f(s[kt][qt][r] - m);
            float r0 = (s[0][qt][0] + s[0][qt][1]) + (s[0][qt][2] + s[0][qt][3]);
            float r1 = (s[1][qt][0] + s[1][qt][1]) + (s[1][qt][2] + s[1][qt][3]);
            float r2 = (s[2][qt][0] + s[2][qt][1]) + (s[2][qt][2] + s[2][qt][3]);
            float r3 = (s[3][qt][0] + s[3][qt][1]) + (s[3][qt][2] + s[3][qt][3]);
            float rs = (r0 + r1) + (r2 + r3);
            rs += __shfl_xor(rs, 16);
            rs += __shfl_xor(rs, 32);
            lrun[qt] += rs;
#pragma unroll
            for (int ks = 0; ks < 2; ++ks) {
                pw[qt][ks][0] = cvt_pk_bf16(s[2 * ks][qt][0], s[2 * ks][qt][1]);
                pw[qt][ks][1] = cvt_pk_bf16(s[2 * ks][qt][2], s[2 * ks][qt][3]);
                pw[qt][ks][2] = cvt_pk_bf16(s[2 * ks + 1][qt][0], s[2 * ks + 1][qt][1]);
                pw[qt][ks][3] = cvt_pk_bf16(s[2 * ks + 1][qt][2], s[2 * ks + 1][qt][3]);
            }
        }

        // ---- ctx^T += V^T * P^T  (k-slot bijection kk = 32ks + 16(j>>2) + 4lg + (j&3)) ----
#pragma unroll
        for (int dt = 0; dt < 4; ++dt) {
            const unsigned short* vrow = vth + (size_t)(dt * 16 + lr) * S_LEN + kb * 64 + 4 * lg;
#pragma unroll
            for (int ks = 0; ks < 2; ++ks) {
                ushort4v lo = *(const ushort4v*)(vrow + 32 * ks);
                ushort4v hi = *(const ushort4v*)(vrow + 32 * ks + 16);
                short8 vf;
                vf[0] = (short)lo[0]; vf[1] = (short)lo[1]; vf[2] = (short)lo[2]; vf[3] = (short)lo[3];
                vf[4] = (short)hi[0]; vf[5] = (short)hi[1]; vf[6] = (short)hi[2]; vf[7] = (short)hi[3];
                __builtin_amdgcn_s_setprio(1);
#pragma unroll
                for (int qt = 0; qt < 4; ++qt) {
                    uint4v w = {pw[qt][ks][0], pw[qt][ks][1], pw[qt][ks][2], pw[qt][ks][3]};
                    ctx[dt][qt] = __builtin_amdgcn_mfma_f32_16x16x32_bf16(vf, __builtin_bit_cast(short8, w),
                                                                          ctx[dt][qt], 0, 0, 0);
                }
                __builtin_amdgcn_s_setprio(0);
            }
        }
    }

    // ---- merge wave1 into wave0 via LDS, then normalize + store ----
    if (wid == 1) {
#pragma unroll
        for (int dt = 0; dt < 4; ++dt)
#pragma unroll
            for (int qt = 0; qt < 4; ++qt) cbuf[dt][qt][lane] = ctx[dt][qt];
#pragma unroll
        for (int qt = 0; qt < 4; ++qt) { mbuf[qt][lane] = mrun[qt]; lbuf[qt][lane] = lrun[qt]; }
    }
    __syncthreads();
    if (wid == 0) {
#pragma unroll
        for (int qt = 0; qt < 4; ++qt) {
            float m1 = mbuf[qt][lane], l1 = lbuf[qt][lane];
            float mM = fmaxf(mrun[qt], m1);
            float s0 = exp2f(mrun[qt] - mM), s1 = exp2f(m1 - mM);
            float linv = 1.0f / (lrun[qt] * s0 + l1 * s1);
            float f0 = s0 * linv, f1 = s1 * linv;
#pragma unroll
            for (int dt = 0; dt < 4; ++dt) {
                f32x4 o1 = cbuf[dt][qt][lane];
                float o0 = ctx[dt][qt][0] * f0 + o1[0] * f1;
                float o1v = ctx[dt][qt][1] * f0 + o1[1] * f1;
                float o2 = ctx[dt][qt][2] * f0 + o1[2] * f1;
                float o3 = ctx[dt][qt][3] * f0 + o1[3] * f1;
                unsigned int lo = (unsigned int)f2bf(o0) | ((unsigned int)f2bf(o1v) << 16);
                unsigned int hi = (unsigned int)f2bf(o2) | ((unsigned int)f2bf(o3) << 16);
                uint2 vv; vv.x = lo; vv.y = hi;
                *(uint2*)(Ctx + (baserow + qb * 64 + qt * 16 + lr) * DMODEL + hcol + dt * 16 + lg * 4) = vv;
            }
        }
    }
}

// ---------------- host launch ----------------
extern "C" void kernel_launch(void* const* d_in, const int* in_sizes, int n_in,
                              void* d_out, int out_size, void* d_ws, size_t ws_size,
                              hipStream_t stream) {
    const float* q_in = (const float*)d_in[0];
    const float* k_in = (const float*)d_in[1];
    const float* v_in = (const float*)d_in[2];
    const float* Wq = (const float*)d_in[4];
    const float* bq = (const float*)d_in[5];
    const float* Wk = (const float*)d_in[6];
    const float* bk = (const float*)d_in[7];
    const float* Wv = (const float*)d_in[8];
    const float* bv = (const float*)d_in[9];
    const float* Wo = (const float*)d_in[10];
    const float* bo = (const float*)d_in[11];

    char* ws = (char*)d_ws;
    const size_t SZ_ACT = (size_t)MTOT * DMODEL * 2;
    const size_t SZ_W = (size_t)DMODEL * DMODEL * 2;
    unsigned short* Xq = (unsigned short*)(ws);
    unsigned short* Xk = (unsigned short*)(ws + SZ_ACT);
    unsigned short* Xv = (unsigned short*)(ws + 2 * SZ_ACT);
    unsigned short* Tq = (unsigned short*)(ws + 3 * SZ_ACT);
    unsigned short* Tk = (unsigned short*)(ws + 3 * SZ_ACT + SZ_W);
    unsigned short* Tv = (unsigned short*)(ws + 3 * SZ_ACT + 2 * SZ_W);
    unsigned short* To = (unsigned short*)(ws + 3 * SZ_ACT + 3 * SZ_W);
    unsigned short* Qp = (unsigned short*)(ws + 3 * SZ_ACT + 4 * SZ_W);
    unsigned short* Kp = (unsigned short*)(ws + 4 * SZ_ACT + 4 * SZ_W);
    unsigned short* Vt = (unsigned short*)(ws + 5 * SZ_ACT + 4 * SZ_W);
    unsigned short* Cx = (unsigned short*)(ws + 6 * SZ_ACT + 4 * SZ_W);

    int n8 = MTOT * DMODEL / 8;
    k_conv3<<<dim3((n8 + 255) / 256, 3), 256, 0, stream>>>(q_in, k_in, v_in, Xq, Xk, Xv, n8);
    k_transpose_w<<<dim3(32, 32, 4), 256, 0, stream>>>(Wq, Wk, Wv, Wo, Tq, Tk, Tv, To);

    k_gemm_qkv<<<dim3(8, 64, 3), 256, 0, stream>>>(Xq, Xk, Xv, Tq, Tk, Tv, bq, bk, bv, Qp, Kp, Vt);

    k_attn<<<dim3((S_LEN / 64) * BATCH * NHEAD), 128, 0, stream>>>(Qp, Kp, Vt, Cx);

    k_gemm_out<<<dim3(8, 64), 256, 0, stream>>>(Cx, To, bo, (float*)d_out);
}

// Round 12
// 438.633 us; speedup vs baseline: 1.2808x; 1.0859x over previous
//
#include <hip/hip_runtime.h>
#include <hip/hip_bf16.h>

#define S_LEN 2048
#define DMODEL 1024
#define NHEAD 16
#define DHEAD 64
#define BATCH 4
#define MTOT (BATCH * S_LEN)   // 8192 rows

typedef __attribute__((ext_vector_type(8))) short short8;
typedef __attribute__((ext_vector_type(8))) unsigned short ushort8;
typedef __attribute__((ext_vector_type(4))) unsigned short ushort4v;
typedef __attribute__((ext_vector_type(4))) unsigned int uint4v;
typedef __attribute__((ext_vector_type(4))) float f32x4;

__device__ __forceinline__ unsigned short f2bf(float x) {
    unsigned int u = __float_as_uint(x);
    u += 0x7FFFu + ((u >> 16) & 1u);   // RNE
    return (unsigned short)(u >> 16);
}

__device__ __forceinline__ unsigned int cvt_pk_bf16(float lo, float hi) {
    unsigned int r;
    asm("v_cvt_pk_bf16_f32 %0, %1, %2" : "=v"(r) : "v"(lo), "v"(hi));
    return r;
}

// guaranteed single-instruction 2^x (exp2f may go through a branchy ocml routine)
__device__ __forceinline__ float fast_exp2(float x) {
    float r;
    asm("v_exp_f32 %0, %1" : "=v"(r) : "v"(x));
    return r;
}

// ---------------- fp32 -> bf16 convert, 3 tensors in one launch ----------------
__global__ __launch_bounds__(256) void k_conv3(const float* __restrict__ s0, const float* __restrict__ s1,
                                               const float* __restrict__ s2,
                                               unsigned short* __restrict__ d0, unsigned short* __restrict__ d1,
                                               unsigned short* __restrict__ d2, int n8) {
    int i = blockIdx.x * 256 + threadIdx.x;
    if (i >= n8) return;
    const float* src = blockIdx.y == 0 ? s0 : (blockIdx.y == 1 ? s1 : s2);
    unsigned short* dst = blockIdx.y == 0 ? d0 : (blockIdx.y == 1 ? d1 : d2);
    const float4* s4 = (const float4*)src;
    float4 a = s4[(size_t)i * 2];
    float4 b = s4[(size_t)i * 2 + 1];
    ushort8 v;
    v[0] = f2bf(a.x); v[1] = f2bf(a.y); v[2] = f2bf(a.z); v[3] = f2bf(a.w);
    v[4] = f2bf(b.x); v[5] = f2bf(b.y); v[6] = f2bf(b.z); v[7] = f2bf(b.w);
    *(ushort8*)(dst + (size_t)i * 8) = v;
}

// ---------------- weight transpose-convert: W[k][n] f32 -> Wt[n][k] bf16 ----------------
__global__ __launch_bounds__(256) void k_transpose_w(const float* __restrict__ W0, const float* __restrict__ W1,
                                                     const float* __restrict__ W2, const float* __restrict__ W3,
                                                     unsigned short* __restrict__ T0, unsigned short* __restrict__ T1,
                                                     unsigned short* __restrict__ T2, unsigned short* __restrict__ T3) {
    const float* src; unsigned short* dst;
    switch (blockIdx.z) {
        case 0: src = W0; dst = T0; break;
        case 1: src = W1; dst = T1; break;
        case 2: src = W2; dst = T2; break;
        default: src = W3; dst = T3; break;
    }
    __shared__ float t[32][33];
    int tx = threadIdx.x & 31, ty = threadIdx.x >> 5;  // 32 x 8
    int n0 = blockIdx.x * 32, k0 = blockIdx.y * 32;
#pragma unroll
    for (int i = 0; i < 32; i += 8)
        t[ty + i][tx] = src[(size_t)(k0 + ty + i) * DMODEL + n0 + tx];
    __syncthreads();
#pragma unroll
    for (int i = 0; i < 32; i += 8)
        dst[(size_t)(n0 + ty + i) * DMODEL + k0 + tx] = f2bf(t[tx][ty + i]);
}

// ================= fused QKV projection GEMM =================
// z==0: Q (alpha folds 1/8 * log2(e) so attention uses exp2 directly)
// z==2 writes V transposed per head: Vt[(b*16+h)*64 + d][s]
__global__ __launch_bounds__(256) void k_gemm_qkv(const unsigned short* __restrict__ Xq,
                                                  const unsigned short* __restrict__ Xk,
                                                  const unsigned short* __restrict__ Xv,
                                                  const unsigned short* __restrict__ Tq,
                                                  const unsigned short* __restrict__ Tk,
                                                  const unsigned short* __restrict__ Tv,
                                                  const float* __restrict__ bqp, const float* __restrict__ bkp,
                                                  const float* __restrict__ bvp,
                                                  unsigned short* __restrict__ Qp, unsigned short* __restrict__ Kp,
                                                  unsigned short* __restrict__ Vt) {
    int z = blockIdx.z;
    const unsigned short* A = z == 0 ? Xq : (z == 1 ? Xk : Xv);
    const unsigned short* Bt = z == 0 ? Tq : (z == 1 ? Tk : Tv);
    const float* bias = z == 0 ? bqp : (z == 1 ? bkp : bvp);
    float alpha = z == 0 ? 0.125f * 1.4426950408889634f : 1.0f;

    __shared__ unsigned short Al[128 * 32];
    __shared__ unsigned short Bl[128 * 32];
    int tid = threadIdx.x;
    int wid = tid >> 6, lane = tid & 63;
    int lr = lane & 15, lg = lane >> 4;
    int lin = blockIdx.y * 8 + blockIdx.x;
    int tile = (lin & 7) * 64 + (lin >> 3);
    int bm = (tile >> 3) * 128, bn = (tile & 7) * 128;
    int wm = (wid >> 1) * 64, wn = (wid & 1) * 64;

    f32x4 acc[4][4];
#pragma unroll
    for (int mt = 0; mt < 4; ++mt)
#pragma unroll
        for (int nt = 0; nt < 4; ++nt) acc[mt][nt] = (f32x4)0.0f;

    for (int k0 = 0; k0 < DMODEL; k0 += 32) {
#pragma unroll
        for (int i = 0; i < 2; ++i) {
            int c = (wid * 2 + i) * 64 + lane;
            int row = c >> 2, cc = c & 3;
            const unsigned short* ga = A + (size_t)(bm + row) * DMODEL + k0 + cc * 8;
            const unsigned short* gb = Bt + (size_t)(bn + row) * DMODEL + k0 + cc * 8;
            __builtin_amdgcn_global_load_lds((const __attribute__((address_space(1))) unsigned int*)ga,
                                             (__attribute__((address_space(3))) unsigned int*)(Al + (wid * 2 + i) * 512),
                                             16, 0, 0);
            __builtin_amdgcn_global_load_lds((const __attribute__((address_space(1))) unsigned int*)gb,
                                             (__attribute__((address_space(3))) unsigned int*)(Bl + (wid * 2 + i) * 512),
                                             16, 0, 0);
        }
        __syncthreads();
        short8 af[4], bf[4];
#pragma unroll
        for (int mt = 0; mt < 4; ++mt)
            af[mt] = *(const short8*)(Al + (wm + mt * 16 + lr) * 32 + lg * 8);
#pragma unroll
        for (int nt = 0; nt < 4; ++nt)
            bf[nt] = *(const short8*)(Bl + (wn + nt * 16 + lr) * 32 + lg * 8);
        __builtin_amdgcn_s_setprio(1);
#pragma unroll
        for (int mt = 0; mt < 4; ++mt)
#pragma unroll
            for (int nt = 0; nt < 4; ++nt)
                acc[mt][nt] = __builtin_amdgcn_mfma_f32_16x16x32_bf16(af[mt], bf[nt], acc[mt][nt], 0, 0, 0);
        __builtin_amdgcn_s_setprio(0);
        __syncthreads();
    }

#pragma unroll
    for (int nt = 0; nt < 4; ++nt) {
        int col = bn + wn + nt * 16 + lr;
        float bv = bias[col];
#pragma unroll
        for (int mt = 0; mt < 4; ++mt) {
#pragma unroll
            for (int r = 0; r < 4; ++r) {
                int row = bm + wm + mt * 16 + lg * 4 + r;
                float v = (acc[mt][nt][r] + bv) * alpha;
                if (z < 2) {
                    unsigned short* dst = z == 0 ? Qp : Kp;
                    dst[(size_t)row * DMODEL + col] = f2bf(v);
                } else {
                    int h = col >> 6, d = col & 63;
                    int b = row >> 11, s = row & 2047;
                    Vt[((size_t)(b * NHEAD + h) * DHEAD + d) * S_LEN + s] = f2bf(v);
                }
            }
        }
    }
}

// ---------------- output projection GEMM (fp32 out) ----------------
__global__ __launch_bounds__(256) void k_gemm_out(const unsigned short* __restrict__ A,
                                                  const unsigned short* __restrict__ Bt,
                                                  const float* __restrict__ bias,
                                                  float* __restrict__ Cout) {
    __shared__ unsigned short Al[128 * 32];
    __shared__ unsigned short Bl[128 * 32];
    int tid = threadIdx.x;
    int wid = tid >> 6, lane = tid & 63;
    int lr = lane & 15, lg = lane >> 4;
    int lin = blockIdx.y * 8 + blockIdx.x;
    int tile = (lin & 7) * 64 + (lin >> 3);
    int bm = (tile >> 3) * 128, bn = (tile & 7) * 128;
    int wm = (wid >> 1) * 64, wn = (wid & 1) * 64;

    f32x4 acc[4][4];
#pragma unroll
    for (int mt = 0; mt < 4; ++mt)
#pragma unroll
        for (int nt = 0; nt < 4; ++nt) acc[mt][nt] = (f32x4)0.0f;

    for (int k0 = 0; k0 < DMODEL; k0 += 32) {
#pragma unroll
        for (int i = 0; i < 2; ++i) {
            int c = (wid * 2 + i) * 64 + lane;
            int row = c >> 2, cc = c & 3;
            const unsigned short* ga = A + (size_t)(bm + row) * DMODEL + k0 + cc * 8;
            const unsigned short* gb = Bt + (size_t)(bn + row) * DMODEL + k0 + cc * 8;
            __builtin_amdgcn_global_load_lds((const __attribute__((address_space(1))) unsigned int*)ga,
                                             (__attribute__((address_space(3))) unsigned int*)(Al + (wid * 2 + i) * 512),
                                             16, 0, 0);
            __builtin_amdgcn_global_load_lds((const __attribute__((address_space(1))) unsigned int*)gb,
                                             (__attribute__((address_space(3))) unsigned int*)(Bl + (wid * 2 + i) * 512),
                                             16, 0, 0);
        }
        __syncthreads();
        short8 af[4], bf[4];
#pragma unroll
        for (int mt = 0; mt < 4; ++mt)
            af[mt] = *(const short8*)(Al + (wm + mt * 16 + lr) * 32 + lg * 8);
#pragma unroll
        for (int nt = 0; nt < 4; ++nt)
            bf[nt] = *(const short8*)(Bl + (wn + nt * 16 + lr) * 32 + lg * 8);
        __builtin_amdgcn_s_setprio(1);
#pragma unroll
        for (int mt = 0; mt < 4; ++mt)
#pragma unroll
            for (int nt = 0; nt < 4; ++nt)
                acc[mt][nt] = __builtin_amdgcn_mfma_f32_16x16x32_bf16(af[mt], bf[nt], acc[mt][nt], 0, 0, 0);
        __builtin_amdgcn_s_setprio(0);
        __syncthreads();
    }

#pragma unroll
    for (int nt = 0; nt < 4; ++nt) {
        int col = bn + wn + nt * 16 + lr;
        float bv = bias[col];
#pragma unroll
        for (int mt = 0; mt < 4; ++mt)
#pragma unroll
            for (int r = 0; r < 4; ++r) {
                int row = bm + wm + mt * 16 + lg * 4 + r;
                Cout[(size_t)row * DMODEL + col] = acc[mt][nt][r] + bv;
            }
    }
}

// ================= causal flash attention, 1 wave per (head, 64-row q-block) =================
// R1 skeleton (fastest measured) + Vt vector V-loads + single-instruction exp2 +
// batched cross-lane reductions (4-wide shfl ILP) + branchless online rescale.
// Scores arrive pre-scaled by log2(e)/8 so softmax uses exp2 directly.
// NOTE: no min-waves arg in launch_bounds — forcing occupancy caused 64/84-VGPR clamps
// and catastrophic scratch spill (R2: 280MB, R4: 1GB per dispatch).
__global__ __launch_bounds__(64) void k_attn(const unsigned short* __restrict__ Qp,
                                             const unsigned short* __restrict__ Kp,
                                             const unsigned short* __restrict__ Vt,
                                             unsigned short* __restrict__ Ctx) {
    int lane = threadIdx.x & 63;
    int lr = lane & 15, lg = lane >> 4;
    int bid = blockIdx.x;                 // 0..2047
    int xcd = bid & 7;
    int j = bid >> 3;                     // 0..255
    int bh = xcd + 8 * (j & 7);           // 8 heads per XCD (K+V ~4MB = one L2)
    int qb = (S_LEN / 64 - 1) - (j >> 3); // biggest q-block first
    int b = bh >> 4, h = bh & 15;
    size_t baserow = (size_t)b * S_LEN;
    int hcol = h * DHEAD;

    short8 qf[4][2];
#pragma unroll
    for (int qt = 0; qt < 4; ++qt)
#pragma unroll
        for (int ks = 0; ks < 2; ++ks)
            qf[qt][ks] = *(const short8*)(Qp + (baserow + qb * 64 + qt * 16 + lr) * DMODEL + hcol + ks * 32 + lg * 8);

    f32x4 ctx[4][4];   // [dt][qt]
#pragma unroll
    for (int dt = 0; dt < 4; ++dt)
#pragma unroll
        for (int qt = 0; qt < 4; ++qt) ctx[dt][qt] = (f32x4)0.0f;

    float mrun[4], lrun[4];
#pragma unroll
    for (int qt = 0; qt < 4; ++qt) { mrun[qt] = -1e30f; lrun[qt] = 0.0f; }

    const unsigned short* vth = Vt + (size_t)bh * DHEAD * S_LEN;

    for (int kb = 0; kb <= qb; ++kb) {
        // ---- S^T = K * Q^T ----
        f32x4 s[4][4];   // [kt][qt]
#pragma unroll
        for (int kt = 0; kt < 4; ++kt)
#pragma unroll
            for (int qt = 0; qt < 4; ++qt) s[kt][qt] = (f32x4)0.0f;
#pragma unroll
        for (int kt = 0; kt < 4; ++kt) {
            short8 kf[2];
#pragma unroll
            for (int ks = 0; ks < 2; ++ks)
                kf[ks] = *(const short8*)(Kp + (baserow + kb * 64 + kt * 16 + lr) * DMODEL + hcol + ks * 32 + lg * 8);
            __builtin_amdgcn_s_setprio(1);
#pragma unroll
            for (int qt = 0; qt < 4; ++qt)
#pragma unroll
                for (int ks = 0; ks < 2; ++ks)
                    s[kt][qt] = __builtin_amdgcn_mfma_f32_16x16x32_bf16(kf[ks], qf[qt][ks], s[kt][qt], 0, 0, 0);
            __builtin_amdgcn_s_setprio(0);
        }

        if (kb == qb) {   // causal mask inside diagonal block
#pragma unroll
            for (int kt = 0; kt < 4; ++kt)
#pragma unroll
                for (int qt = 0; qt < 4; ++qt)
#pragma unroll
                    for (int r = 0; r < 4; ++r)
                        if (kt * 16 + lg * 4 + r > qt * 16 + lr) s[kt][qt][r] = -1e30f;
        }

        // ---- batched local max per qt ----
        float mx[4];
#pragma unroll
        for (int qt = 0; qt < 4; ++qt) {
            float a0 = fmaxf(fmaxf(s[0][qt][0], s[0][qt][1]), fmaxf(s[0][qt][2], s[0][qt][3]));
            float a1 = fmaxf(fmaxf(s[1][qt][0], s[1][qt][1]), fmaxf(s[1][qt][2], s[1][qt][3]));
            float a2 = fmaxf(fmaxf(s[2][qt][0], s[2][qt][1]), fmaxf(s[2][qt][2], s[2][qt][3]));
            float a3 = fmaxf(fmaxf(s[3][qt][0], s[3][qt][1]), fmaxf(s[3][qt][2], s[3][qt][3]));
            mx[qt] = fmaxf(fmaxf(a0, a1), fmaxf(a2, a3));
        }
        // batched cross-lane max: 4 independent shuffles per stage (one wait amortizes)
        float tt[4];
#pragma unroll
        for (int qt = 0; qt < 4; ++qt) tt[qt] = __shfl_xor(mx[qt], 16);
#pragma unroll
        for (int qt = 0; qt < 4; ++qt) mx[qt] = fmaxf(mx[qt], tt[qt]);
#pragma unroll
        for (int qt = 0; qt < 4; ++qt) tt[qt] = __shfl_xor(mx[qt], 32);
#pragma unroll
        for (int qt = 0; qt < 4; ++qt) mx[qt] = fmaxf(mx[qt], tt[qt]);

        // ---- branchless online rescale (scale==1.0 when max unchanged) ----
#pragma unroll
        for (int qt = 0; qt < 4; ++qt) {
            float mnew = fmaxf(mrun[qt], mx[qt]);
            float sc = fast_exp2(mrun[qt] - mnew);
            mrun[qt] = mnew;
            lrun[qt] *= sc;
#pragma unroll
            for (int dt = 0; dt < 4; ++dt)
#pragma unroll
                for (int r = 0; r < 4; ++r) ctx[dt][qt][r] *= sc;
        }

        // ---- exponentiate all scores (single v_exp each) ----
#pragma unroll
        for (int qt = 0; qt < 4; ++qt)
#pragma unroll
            for (int kt = 0; kt < 4; ++kt)
#pragma unroll
                for (int r = 0; r < 4; ++r) s[kt][qt][r] = fast_exp2(s[kt][qt][r] - mrun[qt]);

        // ---- batched row sums ----
        float rs[4];
#pragma unroll
        for (int qt = 0; qt < 4; ++qt) {
            float r0 = (s[0][qt][0] + s[0][qt][1]) + (s[0][qt][2] + s[0][qt][3]);
            float r1 = (s[1][qt][0] + s[1][qt][1]) + (s[1][qt][2] + s[1][qt][3]);
            float r2 = (s[2][qt][0] + s[2][qt][1]) + (s[2][qt][2] + s[2][qt][3]);
            float r3 = (s[3][qt][0] + s[3][qt][1]) + (s[3][qt][2] + s[3][qt][3]);
            rs[qt] = (r0 + r1) + (r2 + r3);
        }
#pragma unroll
        for (int qt = 0; qt < 4; ++qt) tt[qt] = __shfl_xor(rs[qt], 16);
#pragma unroll
        for (int qt = 0; qt < 4; ++qt) rs[qt] += tt[qt];
#pragma unroll
        for (int qt = 0; qt < 4; ++qt) tt[qt] = __shfl_xor(rs[qt], 32);
#pragma unroll
        for (int qt = 0; qt < 4; ++qt) { rs[qt] += tt[qt]; lrun[qt] += rs[qt]; }

        // ---- pack P^T fragments via cvt_pk ----
        uint4v pw[4][2];
#pragma unroll
        for (int qt = 0; qt < 4; ++qt)
#pragma unroll
            for (int ks = 0; ks < 2; ++ks) {
                pw[qt][ks][0] = cvt_pk_bf16(s[2 * ks][qt][0], s[2 * ks][qt][1]);
                pw[qt][ks][1] = cvt_pk_bf16(s[2 * ks][qt][2], s[2 * ks][qt][3]);
                pw[qt][ks][2] = cvt_pk_bf16(s[2 * ks + 1][qt][0], s[2 * ks + 1][qt][1]);
                pw[qt][ks][3] = cvt_pk_bf16(s[2 * ks + 1][qt][2], s[2 * ks + 1][qt][3]);
            }

        // ---- ctx^T += V^T * P^T  (k-slot bijection kk = 32ks + 16(jj>>2) + 4lg + (jj&3)) ----
#pragma unroll
        for (int dt = 0; dt < 4; ++dt) {
            const unsigned short* vrow = vth + (size_t)(dt * 16 + lr) * S_LEN + kb * 64 + 4 * lg;
#pragma unroll
            for (int ks = 0; ks < 2; ++ks) {
                ushort4v lo = *(const ushort4v*)(vrow + 32 * ks);
                ushort4v hi = *(const ushort4v*)(vrow + 32 * ks + 16);
                short8 vf;
                vf[0] = (short)lo[0]; vf[1] = (short)lo[1]; vf[2] = (short)lo[2]; vf[3] = (short)lo[3];
                vf[4] = (short)hi[0]; vf[5] = (short)hi[1]; vf[6] = (short)hi[2]; vf[7] = (short)hi[3];
                __builtin_amdgcn_s_setprio(1);
#pragma unroll
                for (int qt = 0; qt < 4; ++qt)
                    ctx[dt][qt] = __builtin_amdgcn_mfma_f32_16x16x32_bf16(vf, __builtin_bit_cast(short8, pw[qt][ks]),
                                                                          ctx[dt][qt], 0, 0, 0);
                __builtin_amdgcn_s_setprio(0);
            }
        }
    }

    // ---- normalize and store ----
#pragma unroll
    for (int qt = 0; qt < 4; ++qt) {
        float inv = 1.0f / lrun[qt];
#pragma unroll
        for (int dt = 0; dt < 4; ++dt) {
            unsigned int lo = (unsigned int)f2bf(ctx[dt][qt][0] * inv) | ((unsigned int)f2bf(ctx[dt][qt][1] * inv) << 16);
            unsigned int hi = (unsigned int)f2bf(ctx[dt][qt][2] * inv) | ((unsigned int)f2bf(ctx[dt][qt][3] * inv) << 16);
            uint2 vv; vv.x = lo; vv.y = hi;
            *(uint2*)(Ctx + (baserow + qb * 64 + qt * 16 + lr) * DMODEL + hcol + dt * 16 + lg * 4) = vv;
        }
    }
}

// ---------------- host launch ----------------
extern "C" void kernel_launch(void* const* d_in, const int* in_sizes, int n_in,
                              void* d_out, int out_size, void* d_ws, size_t ws_size,
                              hipStream_t stream) {
    const float* q_in = (const float*)d_in[0];
    const float* k_in = (const float*)d_in[1];
    const float* v_in = (const float*)d_in[2];
    const float* Wq = (const float*)d_in[4];
    const float* bq = (const float*)d_in[5];
    const float* Wk = (const float*)d_in[6];
    const float* bk = (const float*)d_in[7];
    const float* Wv = (const float*)d_in[8];
    const float* bv = (const float*)d_in[9];
    const float* Wo = (const float*)d_in[10];
    const float* bo = (const float*)d_in[11];

    char* ws = (char*)d_ws;
    const size_t SZ_ACT = (size_t)MTOT * DMODEL * 2;
    const size_t SZ_W = (size_t)DMODEL * DMODEL * 2;
    unsigned short* Xq = (unsigned short*)(ws);
    unsigned short* Xk = (unsigned short*)(ws + SZ_ACT);
    unsigned short* Xv = (unsigned short*)(ws + 2 * SZ_ACT);
    unsigned short* Tq = (unsigned short*)(ws + 3 * SZ_ACT);
    unsigned short* Tk = (unsigned short*)(ws + 3 * SZ_ACT + SZ_W);
    unsigned short* Tv = (unsigned short*)(ws + 3 * SZ_ACT + 2 * SZ_W);
    unsigned short* To = (unsigned short*)(ws + 3 * SZ_ACT + 3 * SZ_W);
    unsigned short* Qp = (unsigned short*)(ws + 3 * SZ_ACT + 4 * SZ_W);
    unsigned short* Kp = (unsigned short*)(ws + 4 * SZ_ACT + 4 * SZ_W);
    unsigned short* Vt = (unsigned short*)(ws + 5 * SZ_ACT + 4 * SZ_W);
    unsigned short* Cx = (unsigned short*)(ws + 6 * SZ_ACT + 4 * SZ_W);

    int n8 = MTOT * DMODEL / 8;
    k_conv3<<<dim3((n8 + 255) / 256, 3), 256, 0, stream>>>(q_in, k_in, v_in, Xq, Xk, Xv, n8);
    k_transpose_w<<<dim3(32, 32, 4), 256, 0, stream>>>(Wq, Wk, Wv, Wo, Tq, Tk, Tv, To);

    k_gemm_qkv<<<dim3(8, 64, 3), 256, 0, stream>>>(Xq, Xk, Xv, Tq, Tk, Tv, bq, bk, bv, Qp, Kp, Vt);

    k_attn<<<dim3((S_LEN / 64) * BATCH * NHEAD), 64, 0, stream>>>(Qp, Kp, Vt, Cx);

    k_gemm_out<<<dim3(8, 64), 256, 0, stream>>>(Cx, To, bo, (float*)d_out);
}